// Round 17
// baseline (208.491 us; speedup 1.0000x reference)
//
#include <hip/hip_runtime.h>
#include <hip/hip_bf16.h>
#include <cstdint>
#include <cstddef>

typedef unsigned short u16;
typedef unsigned char u8;
typedef long i64;
typedef __bf16 bf16x8 __attribute__((ext_vector_type(8)));
typedef float f32x4 __attribute__((ext_vector_type(4)));
typedef u16 u16x8 __attribute__((ext_vector_type(8)));
typedef u8 u8x16 __attribute__((ext_vector_type(16)));
typedef i64 i64x2 __attribute__((ext_vector_type(2)));

#define NROWS 15360   // B*C = 512*30
#define KDIM 512
#define BDIM 512
#define CDIM 30
#define TDIM 3
#define EDIM 6

typedef __attribute__((address_space(1))) const unsigned int gu32;
typedef __attribute__((address_space(3))) unsigned int lu32;

__device__ __forceinline__ void gload16(const void* g, void* l) {
  __builtin_amdgcn_global_load_lds((gu32*)g, (lu32*)l, 16, 0, 0);
}

__device__ __forceinline__ float bf2f(u16 u) {
  union { unsigned i; float f; } v; v.i = ((unsigned)u) << 16; return v.f;
}
__device__ __forceinline__ u16 f2bf(float f) {
  union { float f; unsigned i; } v; v.f = f;
  unsigned r = v.i + 0x7fffu + ((v.i >> 16) & 1u);
  return (u16)(r >> 16);
}
// fp8 e4m3fn encode, software fallback
__device__ __forceinline__ u8 f2fp8_sw(float v) {
  union { float f; unsigned u; } x; x.f = v;
  unsigned s = (x.u >> 24) & 0x80;
  x.u &= 0x7fffffffu;
  if (x.f < 0.0009765625f) return (u8)s;
  if (x.f > 448.f) return (u8)(s | 0x7e);
  int e; float m = frexpf(x.f, &e);
  if (e < -5) {
    int qq = (int)(x.f * 512.f + 0.5f);
    return (u8)(s | qq);
  }
  int qq = (int)(m * 16.f + 0.5f);
  if (qq == 16) { qq = 8; e++; }
  int E = e + 6;
  if (E >= 16 || (E == 15 && qq - 8 == 7)) return (u8)(s | 0x7e);
  return (u8)(s | (E << 3) | (qq - 8));
}
__device__ __forceinline__ unsigned cvt2fp8(float a, float b) {
#if __has_builtin(__builtin_amdgcn_cvt_pk_fp8_f32)
  return (unsigned)__builtin_amdgcn_cvt_pk_fp8_f32(a, b, 0, false) & 0xffffu;
#else
  return (unsigned)f2fp8_sw(a) | ((unsigned)f2fp8_sw(b) << 8);
#endif
}
// within-64B-group byte permutation: chunk q = {ks0 granule q (8B)} ++ {ks1 granule q (8B)}
__device__ __forceinline__ int permpos(int j) {
  return ((j & 24) << 1) + ((j & 32) >> 2) + (j & 7);
}

// ---------------- merged prep ----------------
__global__ __launch_bounds__(256) void prep_kernel(
    const float* __restrict__ X, u8* __restrict__ Xq,
    const float* __restrict__ fc1, const float* __restrict__ fc2,
    const float* __restrict__ ew1, const float* __restrict__ ew2,
    const float* __restrict__ tw1,
    u8* __restrict__ fc1q, u8* __restrict__ fc2q,
    u8* __restrict__ w1q, u8* __restrict__ w2q, u8* __restrict__ tw1q,
    const float* __restrict__ wg, u8* __restrict__ wgq,
    float* __restrict__ logits) {
  int bid = blockIdx.x;
  if (bid < 3840) {
    int i = bid * 256 + threadIdx.x;          // granule id (8 elems)
    float4 a = *(const float4*)(X + (size_t)i * 8);
    float4 b = *(const float4*)(X + (size_t)i * 8 + 4);
    unsigned p0 = cvt2fp8(a.x * 16.f, a.y * 16.f);
    unsigned p1 = cvt2fp8(a.z * 16.f, a.w * 16.f);
    unsigned p2 = cvt2fp8(b.x * 16.f, b.y * 16.f);
    unsigned p3 = cvt2fp8(b.z * 16.f, b.w * 16.f);
    int row = i >> 6, g = i & 63;
    int pos = (g >> 3) * 64 + (g & 3) * 16 + (g & 4) * 2;  // permpos of granule start
    u8* dst = Xq + (size_t)row * 512 + pos;
    *(unsigned*)dst = p0 | (p1 << 16);
    *(unsigned*)(dst + 4) = p2 | (p3 << 16);
  } else if (bid < 4928) {
    int id = bid - 3840;
    int mid = id >> 6, tile = id & 63;
    const float* src;
    if (mid == 0) src = fc1;
    else if (mid == 1) src = fc2;
    else if (mid < 8) src = ew1 + (size_t)(mid - 2) * 262144;
    else if (mid < 14) src = ew2 + (size_t)(mid - 8) * 262144;
    else src = tw1 + (size_t)(mid - 14) * 262144;
    int tr = (tile >> 3) * 64, tc = (tile & 7) * 64;
    __shared__ float t[64][65];
    int c = threadIdx.x & 63, r0 = threadIdx.x >> 6;
#pragma unroll
    for (int i = 0; i < 16; i++) {
      int r = r0 + i * 4;
      t[r][c] = src[(size_t)(tr + r) * 512 + tc + c];
    }
    __syncthreads();
    u8* dq;
    if (mid == 0) dq = fc1q;
    else if (mid == 1) dq = fc2q;
    else if (mid < 8) dq = w1q + (size_t)(mid - 2) * 262144;
    else if (mid < 14) dq = w2q + (size_t)(mid - 8) * 262144;
    else dq = tw1q + (size_t)(mid - 14) * 262144;
    int pc = tr + permpos(c);   // tr is a multiple of 64
#pragma unroll
    for (int i = 0; i < 16; i++) {
      int r = r0 + i * 4;
      dq[(size_t)(tc + r) * 512 + pc] = (u8)(cvt2fp8(t[c][r] * 64.f, 0.f) & 0xff);
    }
  } else if (bid < 4960) {
    int col = bid - 4928;  // 0..31
    for (int k = threadIdx.x; k < 512; k += 256) {
      float v = 0.f;
      if (col < 18) {
        int t = col / 6, e = col % 6;
        v = wg[(size_t)(t * 512 + k) * 6 + e];
      }
      int pos = (k & ~63) + permpos(k & 63);
      wgq[(size_t)col * 512 + pos] = (u8)(cvt2fp8(v * 64.f, 0.f) & 0xff);
    }
  } else {
    int i = (bid - 4960) * 1024 + threadIdx.x * 4;
    float4 z; z.x = 0.f; z.y = 0.f; z.z = 0.f; z.w = 0.f;
    *(float4*)(logits + i) = z;
  }
}

// ===== generic fp8 GEMM, BM=64 BN=128 BK=128, 4 K-steps, plane-split LDS =====
// Per buf: A plane0 0..4095, A plane1 4096..8191, B plane0 8192..16383,
// B plane1 16384..24575 (each plane: rows x 64B, linear). 6 gloads/step, vmcnt(6).
// Cq = fp8((relu?)(P/1024 + bias) * 16)
template <int RELU>
__global__ __launch_bounds__(256, 2) void gemm_s8(
    const u8* __restrict__ Aq,
    const u8* __restrict__ Bq,
    const float* __restrict__ bias,
    u8* __restrict__ Cq) {
  int nwg = gridDim.x, cpx = nwg >> 3;
  int bid = blockIdx.x;
  int swz = (bid & 7) * cpx + (bid >> 3);
  int bx = swz >> 2, by = swz & 3;
  int brow = bx * 64, bcol = by * 128;

  __shared__ __align__(16) u8 SB8[3][24576];

  int tid = threadIdx.x, lane = tid & 63, w = tid >> 6;
  int l = lane & 15, q = lane >> 4;

  int srow = tid >> 2, sc = tid & 3;
  int scX = sc ^ ((srow >> 1) & 3);
  const u8* Ag = Aq + (size_t)(brow + srow) * 512 + scX * 16;
  const u8* Bg0 = Bq + (size_t)(bcol + srow) * 512 + scX * 16;
  const u8* Bg1 = Bg0 + (size_t)64 * 512;
  int lo = w * 1024;

#define STAGES(buf, kt)                                   \
  do {                                                    \
    const u8* _a = Ag + (kt) * 128;                       \
    gload16(_a, (buf) + lo);                              \
    gload16(_a + 64, (buf) + 4096 + lo);                  \
    const u8* _b0 = Bg0 + (kt) * 128;                     \
    gload16(_b0, (buf) + 8192 + lo);                      \
    gload16(_b0 + 64, (buf) + 16384 + lo);                \
    const u8* _b1 = Bg1 + (kt) * 128;                     \
    gload16(_b1, (buf) + 12288 + lo);                     \
    gload16(_b1 + 64, (buf) + 20480 + lo);                \
  } while (0)

  f32x4 P[4][2];
#pragma unroll
  for (int mi = 0; mi < 4; mi++)
#pragma unroll
    for (int ni = 0; ni < 2; ni++) {
      P[mi][ni][0] = 0.f; P[mi][ni][1] = 0.f; P[mi][ni][2] = 0.f; P[mi][ni][3] = 0.f;
    }

  int xg = q ^ ((l >> 1) & 3);

  STAGES(SB8[0], 0);
  STAGES(SB8[1], 1);
  asm volatile("s_waitcnt vmcnt(6)" ::: "memory");
  __builtin_amdgcn_s_barrier();

  u8 *bc = SB8[0], *bn = SB8[1], *bq = SB8[2];
#pragma unroll
  for (int kt = 0; kt < 4; ++kt) {
    if (kt < 2) STAGES(bq, kt + 2);
#pragma unroll
    for (int ksub = 0; ksub < 2; ++ksub) {
      int pa = ksub * 4096;
      int pb = 8192 + ksub * 8192;
      i64x2 bfv[2], afv[4];
#pragma unroll
      for (int ni = 0; ni < 2; ni++) {
        int col = w * 32 + ni * 16 + l;
        bfv[ni] = *(const i64x2*)&bc[pb + col * 64 + xg * 16];
      }
#pragma unroll
      for (int mi = 0; mi < 4; mi++) {
        int row = mi * 16 + l;
        afv[mi] = *(const i64x2*)&bc[pa + row * 64 + xg * 16];
      }
      __builtin_amdgcn_s_setprio(1);
#pragma unroll
      for (int ks = 0; ks < 2; ++ks)
#pragma unroll
        for (int mi = 0; mi < 4; mi++)
#pragma unroll
          for (int ni = 0; ni < 2; ni++)
            P[mi][ni] = __builtin_amdgcn_mfma_f32_16x16x32_fp8_fp8(
                afv[mi][ks], bfv[ni][ks], P[mi][ni], 0, 0, 0);
      __builtin_amdgcn_s_setprio(0);
    }
    asm volatile("s_waitcnt lgkmcnt(0)" ::: "memory");
    if (kt < 2)
      asm volatile("s_waitcnt vmcnt(6)" ::: "memory");
    else
      asm volatile("s_waitcnt vmcnt(0)" ::: "memory");
    __builtin_amdgcn_s_barrier();
    u8* t_ = bc; bc = bn; bn = bq; bq = t_;
  }
#undef STAGES

  float bvs[2];
#pragma unroll
  for (int ni = 0; ni < 2; ni++) bvs[ni] = bias[bcol + w * 32 + ni * 16 + l];

  u8* S8 = (u8*)&SB8[0][0];   // 64*144 = 9216 B
#pragma unroll
  for (int mi = 0; mi < 4; mi++) {
    int rl = mi * 16 + q * 4;
#pragma unroll
    for (int ni = 0; ni < 2; ni++) {
      int colL = w * 32 + ni * 16 + l;
      int pc = (colL & 64) + permpos(colL & 63);
      float v[4];
#pragma unroll
      for (int rr = 0; rr < 4; rr++) {
        float x = P[mi][ni][rr] * 9.765625e-4f + bvs[ni];
        if (RELU) x = fmaxf(x, 0.f);
        v[rr] = x;
      }
      unsigned p01 = cvt2fp8(v[0] * 16.f, v[1] * 16.f);
      unsigned p23 = cvt2fp8(v[2] * 16.f, v[3] * 16.f);
      S8[(rl + 0) * 144 + pc] = (u8)(p01 & 0xff);
      S8[(rl + 1) * 144 + pc] = (u8)(p01 >> 8);
      S8[(rl + 2) * 144 + pc] = (u8)(p23 & 0xff);
      S8[(rl + 3) * 144 + pc] = (u8)(p23 >> 8);
    }
  }
  __syncthreads();
  {
    int row_ = tid >> 2, cc_ = tid & 3;
#pragma unroll
    for (int j = 0; j < 2; j++)
      *(u8x16*)&Cq[(size_t)(brow + row_) * 512 + bcol + j * 64 + cc_ * 16] =
          *(const u8x16*)&S8[row_ * 144 + j * 64 + cc_ * 16];
  }
}

// ===== gate fp8: glog = hq @ wgq / 1024, top3 softmax -> gates =====
__global__ __launch_bounds__(256) void gate_kernel(const u8* __restrict__ hq,
                                                   const u8* __restrict__ wgq,
                                                   float* __restrict__ gates) {
  __shared__ __align__(16) u8 SBg[2][6144];  // per buf: A 0..4095, B 4096..6143
  __shared__ float Gl[4][16][33];
  int tid = threadIdx.x, lane = tid & 63, w = tid >> 6;
  int l = lane & 15, q = lane >> 4;
  int brow = blockIdx.x * 64;

  int srow = tid >> 2, sc = tid & 3;
  int scA = sc ^ ((srow >> 1) & 3);
  const u8* Ag = hq + (size_t)(brow + srow) * 512 + scA * 16;
  int Brow = srow & 31;
  int scB = sc ^ ((Brow >> 1) & 3);
  const u8* Bg = wgq + (size_t)Brow * 512 + scB * 16;
  int loA = w * 1024;
  int loB = 4096 + w * 1024;   // only waves 0,1

#define STAGEG(buf, kt)                                \
  do {                                                 \
    gload16(Ag + (kt) * 64, (buf) + loA);              \
    if (w < 2) gload16(Bg + (kt) * 64, (buf) + loB);   \
  } while (0)

  f32x4 acc0, acc1;
  acc0[0] = acc0[1] = acc0[2] = acc0[3] = 0.f;
  acc1 = acc0;
  int xg = q ^ ((l >> 1) & 3);
  int arow = w * 16 + l;

  STAGEG(SBg[0], 0);
  asm volatile("s_waitcnt vmcnt(0)" ::: "memory");
  __builtin_amdgcn_s_barrier();

#pragma unroll
  for (int s = 0; s < 8; ++s) {
    u8* bc = SBg[s & 1];
    if (s < 7) STAGEG(SBg[(s + 1) & 1], s + 1);
    i64x2 a = *(const i64x2*)&bc[arow * 64 + xg * 16];
    i64x2 b0 = *(const i64x2*)&bc[4096 + l * 64 + xg * 16];
    i64x2 b1 = *(const i64x2*)&bc[4096 + (16 + l) * 64 + xg * 16];
#pragma unroll
    for (int ks = 0; ks < 2; ++ks) {
      acc0 = __builtin_amdgcn_mfma_f32_16x16x32_fp8_fp8(a[ks], b0[ks], acc0, 0, 0, 0);
      acc1 = __builtin_amdgcn_mfma_f32_16x16x32_fp8_fp8(a[ks], b1[ks], acc1, 0, 0, 0);
    }
    asm volatile("s_waitcnt lgkmcnt(0)" ::: "memory");
    asm volatile("s_waitcnt vmcnt(0)" ::: "memory");
    __builtin_amdgcn_s_barrier();
  }
#undef STAGEG

#pragma unroll
  for (int rr = 0; rr < 4; rr++) {
    Gl[w][q * 4 + rr][l] = acc0[rr] * 9.765625e-4f;
    Gl[w][q * 4 + rr][16 + l] = acc1[rr] * 9.765625e-4f;
  }
  __syncthreads();

  if (lane < 16) {
    int R = brow + w * 16 + lane;
    int b = R / CDIM, c = R % CDIM;
    for (int t = 0; t < 3; t++) {
      float g[6];
#pragma unroll
      for (int e = 0; e < 6; e++) g[e] = Gl[w][lane][t * 6 + e];
      float out[6] = {0, 0, 0, 0, 0, 0};
      int idx[3]; float val[3];
      unsigned used = 0;
      for (int kk = 0; kk < 3; kk++) {
        int best = 0; float bv = -1e30f;
        for (int e = 0; e < 6; e++)
          if (!((used >> e) & 1) && g[e] > bv) { bv = g[e]; best = e; }
        used |= 1u << best; idx[kk] = best; val[kk] = bv;
      }
      float mx = val[0];
      float s = 0.f, ex[3];
      for (int kk = 0; kk < 3; kk++) { ex[kk] = expf(val[kk] - mx); s += ex[kk]; }
      for (int kk = 0; kk < 3; kk++) out[idx[kk]] = ex[kk] / s;
      float* gp = &gates[(size_t)((b * TDIM + t) * CDIM + c) * EDIM];
      for (int e = 0; e < 6; e++) gp[e] = out[e];
    }
  }
}

// ===== W1 fp8: 128x256 tile, BK=64, 8 K-steps, triple-buffer counted vmcnt =====
__global__ __launch_bounds__(512, 4) void gemm256q(
    const u8* __restrict__ Aq,
    const u8* __restrict__ Bq,
    const float* __restrict__ bias,
    u8* __restrict__ Cq,
    int nby) {
  int nwg = gridDim.x;
  int cpx = nwg >> 3;
  int bid = blockIdx.x;
  int swz = (bid & 7) * cpx + (bid >> 3);
  int bx = swz / nby, by = swz % nby;
  int brow = bx * 128, bcol = by * 256;

  __shared__ __align__(16) u8 SB8[3][24576];  // A 0..8191, B 8192..24575

  int tid = threadIdx.x, lane = tid & 63, w = tid >> 6;
  int wm = w >> 2, wn = w & 3;
  int l = lane & 15, q = lane >> 4;

  int srow = tid >> 2, sc = tid & 3;
  int scX = sc ^ ((srow >> 1) & 3);
  const u8* Ag = Aq + (size_t)(brow + srow) * 512 + scX * 16;
  const u8* Bg0 = Bq + (size_t)(bcol + srow) * 512 + scX * 16;
  const u8* Bg1 = Bg0 + (size_t)128 * 512;
  int lo = w * 1024;

#define STAGEQ(buf, kt)                                \
  do {                                                 \
    gload16(Ag + (kt) * 64, (buf) + lo);               \
    gload16(Bg0 + (kt) * 64, (buf) + 8192 + lo);       \
    gload16(Bg1 + (kt) * 64, (buf) + 16384 + lo);      \
  } while (0)

  f32x4 acc[4][4];
#pragma unroll
  for (int m = 0; m < 4; m++)
#pragma unroll
    for (int n = 0; n < 4; n++) {
      acc[m][n][0] = 0.f; acc[m][n][1] = 0.f; acc[m][n][2] = 0.f; acc[m][n][3] = 0.f;
    }

  int xg = q ^ ((l >> 1) & 3);

  STAGEQ(SB8[0], 0);
  STAGEQ(SB8[1], 1);
  asm volatile("s_waitcnt vmcnt(3)" ::: "memory");
  __builtin_amdgcn_s_barrier();

  u8 *bc = SB8[0], *bn = SB8[1], *bq = SB8[2];
#pragma unroll
  for (int kt = 0; kt < 8; ++kt) {
    if (kt < 6) STAGEQ(bq, kt + 2);
    i64x2 afv[4], bfv[4];
#pragma unroll
    for (int mi = 0; mi < 4; mi++) {
      int row = wm * 64 + mi * 16 + l;
      afv[mi] = *(const i64x2*)&bc[row * 64 + xg * 16];
    }
#pragma unroll
    for (int ni = 0; ni < 4; ni++) {
      int col = wn * 64 + ni * 16 + l;
      bfv[ni] = *(const i64x2*)&bc[8192 + col * 64 + xg * 16];
    }
    __builtin_amdgcn_s_setprio(1);
#pragma unroll
    for (int ks = 0; ks < 2; ++ks)
#pragma unroll
      for (int mi = 0; mi < 4; mi++)
#pragma unroll
        for (int ni = 0; ni < 4; ni++)
          acc[mi][ni] = __builtin_amdgcn_mfma_f32_16x16x32_fp8_fp8(
              afv[mi][ks], bfv[ni][ks], acc[mi][ni], 0, 0, 0);
    __builtin_amdgcn_s_setprio(0);
    asm volatile("s_waitcnt lgkmcnt(0)" ::: "memory");
    if (kt < 6)
      asm volatile("s_waitcnt vmcnt(3)" ::: "memory");
    else
      asm volatile("s_waitcnt vmcnt(0)" ::: "memory");
    __builtin_amdgcn_s_barrier();
    u8* t_ = bc; bc = bn; bn = bq; bq = t_;
  }
#undef STAGEQ

  u8* S8 = (u8*)&SB8[0][0];
  float bvs[4];
#pragma unroll
  for (int n = 0; n < 4; n++) bvs[n] = bias[bcol + wn * 64 + n * 16 + l];
#pragma unroll
  for (int m = 0; m < 4; m++) {
    int rl = wm * 64 + m * 16 + q * 4;
#pragma unroll
    for (int n = 0; n < 4; n++) {
      int pc = wn * 64 + permpos(n * 16 + l);
      float v0 = fmaxf(acc[m][n][0] * 9.765625e-4f + bvs[n], 0.f) * 16.f;
      float v1 = fmaxf(acc[m][n][1] * 9.765625e-4f + bvs[n], 0.f) * 16.f;
      float v2 = fmaxf(acc[m][n][2] * 9.765625e-4f + bvs[n], 0.f) * 16.f;
      float v3 = fmaxf(acc[m][n][3] * 9.765625e-4f + bvs[n], 0.f) * 16.f;
      unsigned p01 = cvt2fp8(v0, v1);
      unsigned p23 = cvt2fp8(v2, v3);
      S8[(rl + 0) * 264 + pc] = (u8)(p01 & 0xff);
      S8[(rl + 1) * 264 + pc] = (u8)(p01 >> 8);
      S8[(rl + 2) * 264 + pc] = (u8)(p23 & 0xff);
      S8[(rl + 3) * 264 + pc] = (u8)(p23 >> 8);
    }
  }
  __syncthreads();
  int row = tid >> 2, cc = tid & 3;
#pragma unroll
  for (int j = 0; j < 4; j++)
    *(u8x16*)&Cq[(size_t)(brow + row) * 3072 + bcol + cc * 64 + j * 16] =
        *(const u8x16*)&S8[row * 264 + cc * 64 + j * 16];
}

// ===== fused W2 + gated combine, fp8, BK=128 plane-split (24 K-steps) =====
// launch_bounds MUST stay (256,2): (256,4) caps VGPR at 64 -> accumulator spill (R8).
__global__ __launch_bounds__(256, 2) void gemm_w2c(
    const u8* __restrict__ eh,       // [15360][3072] fp8 (x16), permuted
    const u8* __restrict__ W2q,      // [6][512 col][512 k] fp8 (x64), permuted
    const float* __restrict__ eb2,   // [6][512]
    const float* __restrict__ gates, // [(b*3+t)*30+c][6]
    u8* __restrict__ yq) {           // [3][15360][512] fp8 (x32), permuted
  int nwg = gridDim.x, cpx = nwg >> 3;
  int bid = blockIdx.x;
  int swz = (bid & 7) * cpx + (bid >> 3);
  int bx = swz >> 2, by = swz & 3;
  int brow = bx * 64, bcol = by * 128;

  __shared__ __align__(16) u8 SB8[3][24576];
  __shared__ u16 glds[64 * 18];

  int tid = threadIdx.x, lane = tid & 63, w = tid >> 6;
  int l = lane & 15, q = lane >> 4;

  for (int i = tid; i < 64 * 18; i += 256) {
    int r = i / 18, te = i % 18;
    int gr = brow + r, b = gr / CDIM, c = gr % CDIM;
    int t = te / 6, e = te % 6;
    glds[i] = f2bf(gates[((size_t)(b * TDIM + t) * CDIM + c) * EDIM + e]);
  }
  float b2all[2][6];
#pragma unroll
  for (int ni = 0; ni < 2; ni++) {
    int col = bcol + w * 32 + ni * 16 + l;
#pragma unroll
    for (int e = 0; e < 6; e++) b2all[ni][e] = eb2[e * 512 + col];
  }

  int srow = tid >> 2, sc = tid & 3;
  int scX = sc ^ ((srow >> 1) & 3);
  const u8* Ag = eh + (size_t)(brow + srow) * 3072 + scX * 16;
  const u8* Bg0 = W2q + (size_t)(bcol + srow) * 512 + scX * 16;
  const u8* Bg1 = Bg0 + (size_t)64 * 512;
  int lo = w * 1024;

#define STAGEW(buf, s2)                                                   \
  do {                                                                    \
    int _e2 = (s2) >> 2, _k2 = (s2) & 3;                                  \
    const u8* _a = Ag + _e2 * 512 + _k2 * 128;                            \
    gload16(_a, (buf) + lo);                                              \
    gload16(_a + 64, (buf) + 4096 + lo);                                  \
    const u8* _b0 = Bg0 + (size_t)_e2 * 262144 + _k2 * 128;               \
    gload16(_b0, (buf) + 8192 + lo);                                      \
    gload16(_b0 + 64, (buf) + 16384 + lo);                                \
    const u8* _b1 = Bg1 + (size_t)_e2 * 262144 + _k2 * 128;               \
    gload16(_b1, (buf) + 12288 + lo);                                     \
    gload16(_b1 + 64, (buf) + 20480 + lo);                                \
  } while (0)

  f32x4 P[4][2], aY0[4][2], aY1[4][2], aY2[4][2];
#pragma unroll
  for (int mi = 0; mi < 4; mi++)
#pragma unroll
    for (int ni = 0; ni < 2; ni++) {
      P[mi][ni][0] = P[mi][ni][1] = P[mi][ni][2] = P[mi][ni][3] = 0.f;
      aY0[mi][ni] = P[mi][ni]; aY1[mi][ni] = P[mi][ni]; aY2[mi][ni] = P[mi][ni];
    }

  int xg = q ^ ((l >> 1) & 3);

  STAGEW(SB8[0], 0);
  STAGEW(SB8[1], 1);
  asm volatile("s_waitcnt vmcnt(6)" ::: "memory");
  __builtin_amdgcn_s_barrier();

  u8 *bc = SB8[0], *bn = SB8[1], *bq = SB8[2];
  for (int e = 0; e < 6; ++e) {
#pragma unroll
    for (int kt = 0; kt < 4; ++kt) {
      int s = e * 4 + kt;
      if (s < 22) STAGEW(bq, s + 2);
#pragma unroll
      for (int ksub = 0; ksub < 2; ++ksub) {
        int pa = ksub * 4096;
        int pb = 8192 + ksub * 8192;
        i64x2 bfv[2], afv[4];
#pragma unroll
        for (int ni = 0; ni < 2; ni++) {
          int col = w * 32 + ni * 16 + l;
          bfv[ni] = *(const i64x2*)&bc[pb + col * 64 + xg * 16];
        }
#pragma unroll
        for (int mi = 0; mi < 4; mi++) {
          int row = mi * 16 + l;
          afv[mi] = *(const i64x2*)&bc[pa + row * 64 + xg * 16];
        }
        __builtin_amdgcn_s_setprio(1);
#pragma unroll
        for (int ks = 0; ks < 2; ++ks)
#pragma unroll
          for (int mi = 0; mi < 4; mi++)
#pragma unroll
            for (int ni = 0; ni < 2; ni++)
              P[mi][ni] = __builtin_amdgcn_mfma_f32_16x16x32_fp8_fp8(
                  afv[mi][ks], bfv[ni][ks], P[mi][ni], 0, 0, 0);
        __builtin_amdgcn_s_setprio(0);
      }
      asm volatile("s_waitcnt lgkmcnt(0)" ::: "memory");
      if (s < 22)
        asm volatile("s_waitcnt vmcnt(6)" ::: "memory");
      else
        asm volatile("s_waitcnt vmcnt(0)" ::: "memory");
      __builtin_amdgcn_s_barrier();
      u8* t_ = bc; bc = bn; bn = bq; bq = t_;
    }
    // expert boundary: descale (1/(16*64)), add bias, fold with gates
#pragma unroll
    for (int mi = 0; mi < 4; mi++) {
#pragma unroll
      for (int rr = 0; rr < 4; rr++) {
        int row = mi * 16 + q * 4 + rr;
        float g0 = bf2f(glds[row * 18 + e]);
        float g1 = bf2f(glds[row * 18 + 6 + e]);
        float g2 = bf2f(glds[row * 18 + 12 + e]);
#pragma unroll
        for (int ni = 0; ni < 2; ni++) {
          float p = P[mi][ni][rr] * 9.765625e-4f + b2all[ni][e];
          aY0[mi][ni][rr] += g0 * p;
          aY1[mi][ni][rr] += g1 * p;
          aY2[mi][ni][rr] += g2 * p;
          P[mi][ni][rr] = 0.f;
        }
      }
    }
  }
#undef STAGEW

  u8* S8 = (u8*)&SB8[0][0];
#define EPI(AY, t)                                                          \
  do {                                                                      \
    _Pragma("unroll") for (int mi = 0; mi < 4; mi++) {                      \
      int rl = mi * 16 + q * 4;                                             \
      _Pragma("unroll") for (int ni = 0; ni < 2; ni++) {                    \
        int colL = w * 32 + ni * 16 + l;                                    \
        int pc = (colL & 64) + permpos(colL & 63);                          \
        unsigned p01 = cvt2fp8(AY[mi][ni][0] * 32.f, AY[mi][ni][1] * 32.f); \
        unsigned p23 = cvt2fp8(AY[mi][ni][2] * 32.f, AY[mi][ni][3] * 32.f); \
        S8[(rl + 0) * 144 + pc] = (u8)(p01 & 0xff);                         \
        S8[(rl + 1) * 144 + pc] = (u8)(p01 >> 8);                          \
        S8[(rl + 2) * 144 + pc] = (u8)(p23 & 0xff);                         \
        S8[(rl + 3) * 144 + pc] = (u8)(p23 >> 8);                          \
      }                                                                     \
    }                                                                       \
    __syncthreads();                                                        \
    {                                                                       \
      int row_ = tid >> 2, cc_ = tid & 3;                                   \
      _Pragma("unroll") for (int j = 0; j < 2; j++)                         \
        *(u8x16*)&yq[((size_t)(t) * NROWS + brow + row_) * 512 + bcol +     \
                     j * 64 + cc_ * 16] =                                   \
            *(const u8x16*)&S8[row_ * 144 + j * 64 + cc_ * 16];             \
    }                                                                       \
    __syncthreads();                                                        \
  } while (0)
  EPI(aY0, 0);
  EPI(aY1, 1);
  EPI(aY2, 2);
#undef EPI
}

// ===== tower fp8, BK=128 plane-split (4 K-steps): logits += relu(y@tw1+tb1).tw2 =====
__global__ __launch_bounds__(256, 2) void gemm_tower(
    const u8* __restrict__ yq,
    const u8* __restrict__ tw1q,
    const float* __restrict__ tb1, const float* __restrict__ tw2,
    float* __restrict__ logits) {
  int t = blockIdx.z;
  const u8* A = yq + (size_t)t * NROWS * 512;
  const u8* BT = tw1q + (size_t)t * 262144;

  int nwg = gridDim.x, cpx = nwg >> 3;
  int bid = blockIdx.x;
  int swz = (bid & 7) * cpx + (bid >> 3);
  int bx = swz >> 2, by = swz & 3;
  int brow = bx * 64, bcol = by * 128;

  __shared__ __align__(16) u8 SB8[3][24576];

  int tid = threadIdx.x, lane = tid & 63, w = tid >> 6;
  int l = lane & 15, q = lane >> 4;

  int srow = tid >> 2, sc = tid & 3;
  int scX = sc ^ ((srow >> 1) & 3);
  const u8* Ag = A + (size_t)(brow + srow) * 512 + scX * 16;
  const u8* Bg0 = BT + (size_t)(bcol + srow) * 512 + scX * 16;
  const u8* Bg1 = Bg0 + (size_t)64 * 512;
  int lo = w * 1024;

#define STAGET(buf, kt)                                   \
  do {                                                    \
    const u8* _a = Ag + (kt) * 128;                       \
    gload16(_a, (buf) + lo);                              \
    gload16(_a + 64, (buf) + 4096 + lo);                  \
    const u8* _b0 = Bg0 + (kt) * 128;                     \
    gload16(_b0, (buf) + 8192 + lo);                      \
    gload16(_b0 + 64, (buf) + 16384 + lo);                \
    const u8* _b1 = Bg1 + (kt) * 128;                     \
    gload16(_b1, (buf) + 12288 + lo);                     \
    gload16(_b1 + 64, (buf) + 20480 + lo);                \
  } while (0)

  f32x4 P[4][2];
#pragma unroll
  for (int mi = 0; mi < 4; mi++)
#pragma unroll
    for (int ni = 0; ni < 2; ni++) {
      P[mi][ni][0] = 0.f; P[mi][ni][1] = 0.f; P[mi][ni][2] = 0.f; P[mi][ni][3] = 0.f;
    }

  int xg = q ^ ((l >> 1) & 3);

  STAGET(SB8[0], 0);
  STAGET(SB8[1], 1);
  asm volatile("s_waitcnt vmcnt(6)" ::: "memory");
  __builtin_amdgcn_s_barrier();

  u8 *bc = SB8[0], *bn = SB8[1], *bq = SB8[2];
#pragma unroll
  for (int kt = 0; kt < 4; ++kt) {
    if (kt < 2) STAGET(bq, kt + 2);
#pragma unroll
    for (int ksub = 0; ksub < 2; ++ksub) {
      int pa = ksub * 4096;
      int pb = 8192 + ksub * 8192;
      i64x2 bfv[2], afv[4];
#pragma unroll
      for (int ni = 0; ni < 2; ni++) {
        int col = w * 32 + ni * 16 + l;
        bfv[ni] = *(const i64x2*)&bc[pb + col * 64 + xg * 16];
      }
#pragma unroll
      for (int mi = 0; mi < 4; mi++) {
        int row = mi * 16 + l;
        afv[mi] = *(const i64x2*)&bc[pa + row * 64 + xg * 16];
      }
      __builtin_amdgcn_s_setprio(1);
#pragma unroll
      for (int ks = 0; ks < 2; ++ks)
#pragma unroll
        for (int mi = 0; mi < 4; mi++)
#pragma unroll
          for (int ni = 0; ni < 2; ni++)
            P[mi][ni] = __builtin_amdgcn_mfma_f32_16x16x32_fp8_fp8(
                afv[mi][ks], bfv[ni][ks], P[mi][ni], 0, 0, 0);
      __builtin_amdgcn_s_setprio(0);
    }
    asm volatile("s_waitcnt lgkmcnt(0)" ::: "memory");
    if (kt < 2)
      asm volatile("s_waitcnt vmcnt(6)" ::: "memory");
    else
      asm volatile("s_waitcnt vmcnt(0)" ::: "memory");
    __builtin_amdgcn_s_barrier();
    u8* t_ = bc; bc = bn; bn = bq; bq = t_;
  }
#undef STAGET

  float bvs[2], tws[2];
#pragma unroll
  for (int ni = 0; ni < 2; ni++) {
    int col = bcol + w * 32 + ni * 16 + l;
    bvs[ni] = tb1[t * 512 + col];
    tws[ni] = tw2[t * 512 + col];
  }
#pragma unroll
  for (int mi = 0; mi < 4; mi++) {
#pragma unroll
    for (int rr = 0; rr < 4; rr++) {
      float s = 0.f;
#pragma unroll
      for (int ni = 0; ni < 2; ni++) {
        float v = P[mi][ni][rr] * 4.8828125e-4f + bvs[ni];
        v = fmaxf(v, 0.f);
        s += v * tws[ni];
      }
      s += __shfl_xor(s, 1, 64);
      s += __shfl_xor(s, 2, 64);
      s += __shfl_xor(s, 4, 64);
      s += __shfl_xor(s, 8, 64);
      if (l == 0) {
        int row = brow + mi * 16 + q * 4 + rr;
        int b = row / CDIM, c = row % CDIM;
        atomicAdd(&logits[(size_t)(b * TDIM + t) * CDIM + c], s);
      }
    }
  }
}

// ---------------- loss: one wave per b ----------------
__global__ __launch_bounds__(64) void loss_kernel(const float* __restrict__ scores,
                                                  const float* __restrict__ logits,
                                                  const float* __restrict__ gates,
                                                  const float* __restrict__ tb2,
                                                  float* __restrict__ out) {
  int b = blockIdx.x;
  int lane = threadIdx.x;
  float bce_sum = 0.f;
  float aux = 0.f;
  for (int t = 0; t < 3; t++) {
    float sc = (lane < CDIM) ? scores[(size_t)(b * TDIM + t) * CDIM + lane] : -1e30f;
    float mx = sc;
    for (int off = 32; off; off >>= 1) mx = fmaxf(mx, __shfl_xor(mx, off, 64));
    float lab = (lane < CDIM && sc == mx) ? 1.f : 0.f;
    float lg = (lane < CDIM) ? (logits[(size_t)(b * TDIM + t) * CDIM + lane] + tb2[t]) : 0.f;
    float bce = (lane < CDIM) ? (fmaxf(lg, 0.f) - lg * lab + log1pf(expf(-fabsf(lg)))) : 0.f;
    for (int off = 32; off; off >>= 1) bce += __shfl_xor(bce, off, 64);
    bce_sum += bce / (float)CDIM;

    float impv[6];
    float meansum = 0.f;
#pragma unroll
    for (int e = 0; e < 6; e++) {
      float gsum = (lane < CDIM) ? gates[(size_t)((b * TDIM + t) * CDIM + lane) * EDIM + e] : 0.f;
      for (int off = 32; off; off >>= 1) gsum += __shfl_xor(gsum, off, 64);
      impv[e] = gsum;
      meansum += gsum;
    }
    float mean = meansum / 6.f;
    float var = 0.f;
#pragma unroll
    for (int e = 0; e < 6; e++) { float d = impv[e] - mean; var += d * d; }
    var /= 6.f;
    aux += var / (mean * mean + 1e-10f);
  }
  float res = bce_sum / 3.f + 0.01f * aux;
  if (lane == 0) atomicAdd(out, res / (float)BDIM);
}

// ---------------- host ----------------
extern "C" void kernel_launch(void* const* d_in, const int* in_sizes, int n_in,
                              void* d_out, int out_size, void* d_ws, size_t ws_size,
                              hipStream_t stream) {
  const float* X = (const float*)d_in[0];
  const float* scores = (const float*)d_in[1];
  const float* fc1_w = (const float*)d_in[2];
  const float* fc1_b = (const float*)d_in[3];
  const float* fc2_w = (const float*)d_in[4];
  const float* fc2_b = (const float*)d_in[5];
  const float* w_gate = (const float*)d_in[6];
  const float* ew1 = (const float*)d_in[7];
  const float* eb1 = (const float*)d_in[8];
  const float* ew2 = (const float*)d_in[9];
  const float* eb2 = (const float*)d_in[10];
  const float* tw1 = (const float*)d_in[11];
  const float* tb1 = (const float*)d_in[12];
  const float* tw2 = (const float*)d_in[13];
  const float* tb2 = (const float*)d_in[14];
  float* out = (float*)d_out;

  // workspace layout (all disjoint)
  u8* fc1q = (u8*)d_ws;                          // 262144
  u8* fc2q = fc1q + 262144;                      // 262144
  u8* w1q = fc2q + 262144;                       // 6*262144
  u8* w2q = w1q + (size_t)6 * 262144;            // 6*262144
  u8* tw1q = w2q + (size_t)6 * 262144;           // 3*262144
  u8* wgq = tw1q + (size_t)3 * 262144;           // 32*512
  u8* Xq = wgq + (size_t)32 * 512;               // [15360][512]
  u8* A1q = Xq + (size_t)NROWS * 512;            // [15360][512]
  u8* hq = A1q + (size_t)NROWS * 512;            // [15360][512]
  u8* ehq = hq + (size_t)NROWS * 512;            // [15360][3072]
  u8* yq = ehq + (size_t)NROWS * 3072;           // [3][15360][512]
  float* gates = (float*)(yq + (size_t)TDIM * NROWS * 512);
  float* logits = gates + (size_t)BDIM * TDIM * CDIM * EDIM;

  hipMemsetAsync(d_out, 0, sizeof(float) * out_size, stream);

  // merged prep: X -> fp8, all weights + gate weights -> fp8, zero logits
  prep_kernel<<<5005, 256, 0, stream>>>(X, Xq, fc1_w, fc2_w, ew1, ew2, tw1,
                                        fc1q, fc2q, w1q, w2q, tw1q, w_gate, wgq, logits);

  // shared bottom fp8 (960 blocks of 64x128, BK=128, 4 K-steps)
  gemm_s8<1><<<dim3(960), 256, 0, stream>>>(Xq, fc1q, fc1_b, A1q);   // relu
  gemm_s8<0><<<dim3(960), 256, 0, stream>>>(A1q, fc2q, fc2_b, hq);   // no relu

  // gating fp8 (240 blocks)
  gate_kernel<<<240, 256, 0, stream>>>(hq, wgq, gates);

  // experts W1 fp8: merged N=3072 (1440 blocks of 128x256, 8 K-steps) -> ehq
  gemm256q<<<dim3(1440), 512, 0, stream>>>(hq, w1q, eb1, ehq, 12);

  // experts W2 + gated combine, fp8 (960 blocks of 64x128, BK=128, 24 K-steps) -> yq
  gemm_w2c<<<dim3(960), 256, 0, stream>>>(ehq, w2q, eb2, gates, yq);

  // towers fp8 (960 x 3 blocks of 64x128, BK=128, 4 K-steps) -> logits (atomic)
  gemm_tower<<<dim3(960, 1, 3), 256, 0, stream>>>(yq, tw1q, tb1, tw2, logits);

  // loss
  loss_kernel<<<BDIM, 64, 0, stream>>>(scores, logits, gates, tb2, out);
}

// Round 18
// 204.743 us; speedup vs baseline: 1.0183x; 1.0183x over previous
//
#include <hip/hip_runtime.h>
#include <hip/hip_bf16.h>
#include <cstdint>
#include <cstddef>

typedef unsigned short u16;
typedef unsigned char u8;
typedef long i64;
typedef __bf16 bf16x8 __attribute__((ext_vector_type(8)));
typedef float f32x4 __attribute__((ext_vector_type(4)));
typedef u16 u16x8 __attribute__((ext_vector_type(8)));
typedef u8 u8x16 __attribute__((ext_vector_type(16)));
typedef i64 i64x2 __attribute__((ext_vector_type(2)));

#define NROWS 15360   // B*C = 512*30
#define KDIM 512
#define BDIM 512
#define CDIM 30
#define TDIM 3
#define EDIM 6

typedef __attribute__((address_space(1))) const unsigned int gu32;
typedef __attribute__((address_space(3))) unsigned int lu32;

__device__ __forceinline__ void gload16(const void* g, void* l) {
  __builtin_amdgcn_global_load_lds((gu32*)g, (lu32*)l, 16, 0, 0);
}

__device__ __forceinline__ float bf2f(u16 u) {
  union { unsigned i; float f; } v; v.i = ((unsigned)u) << 16; return v.f;
}
__device__ __forceinline__ u16 f2bf(float f) {
  union { float f; unsigned i; } v; v.f = f;
  unsigned r = v.i + 0x7fffu + ((v.i >> 16) & 1u);
  return (u16)(r >> 16);
}
// fp8 e4m3fn encode, software fallback
__device__ __forceinline__ u8 f2fp8_sw(float v) {
  union { float f; unsigned u; } x; x.f = v;
  unsigned s = (x.u >> 24) & 0x80;
  x.u &= 0x7fffffffu;
  if (x.f < 0.0009765625f) return (u8)s;
  if (x.f > 448.f) return (u8)(s | 0x7e);
  int e; float m = frexpf(x.f, &e);
  if (e < -5) {
    int qq = (int)(x.f * 512.f + 0.5f);
    return (u8)(s | qq);
  }
  int qq = (int)(m * 16.f + 0.5f);
  if (qq == 16) { qq = 8; e++; }
  int E = e + 6;
  if (E >= 16 || (E == 15 && qq - 8 == 7)) return (u8)(s | 0x7e);
  return (u8)(s | (E << 3) | (qq - 8));
}
__device__ __forceinline__ unsigned cvt2fp8(float a, float b) {
#if __has_builtin(__builtin_amdgcn_cvt_pk_fp8_f32)
  return (unsigned)__builtin_amdgcn_cvt_pk_fp8_f32(a, b, 0, false) & 0xffffu;
#else
  return (unsigned)f2fp8_sw(a) | ((unsigned)f2fp8_sw(b) << 8);
#endif
}
// within-64B-group byte permutation: chunk q = {ks0 granule q (8B)} ++ {ks1 granule q (8B)}
__device__ __forceinline__ int permpos(int j) {
  return ((j & 24) << 1) + ((j & 32) >> 2) + (j & 7);
}

// ---------------- merged prep ----------------
// bid 0..3839: cvt X fp32 -> fp8 x16 permuted
// bid 3840..4927: weight tiles -> fp8 x64 permuted (fc1,fc2,w1,w2,tw1)
// bid 4928..4959: gate weight col -> wgq fp8 x64 permuted (cols 18..31 zero)
// bid 4960..5004: zero logits
__global__ __launch_bounds__(256) void prep_kernel(
    const float* __restrict__ X, u8* __restrict__ Xq,
    const float* __restrict__ fc1, const float* __restrict__ fc2,
    const float* __restrict__ ew1, const float* __restrict__ ew2,
    const float* __restrict__ tw1,
    u8* __restrict__ fc1q, u8* __restrict__ fc2q,
    u8* __restrict__ w1q, u8* __restrict__ w2q, u8* __restrict__ tw1q,
    const float* __restrict__ wg, u8* __restrict__ wgq,
    float* __restrict__ logits) {
  int bid = blockIdx.x;
  if (bid < 3840) {
    int i = bid * 256 + threadIdx.x;          // granule id (8 elems)
    float4 a = *(const float4*)(X + (size_t)i * 8);
    float4 b = *(const float4*)(X + (size_t)i * 8 + 4);
    unsigned p0 = cvt2fp8(a.x * 16.f, a.y * 16.f);
    unsigned p1 = cvt2fp8(a.z * 16.f, a.w * 16.f);
    unsigned p2 = cvt2fp8(b.x * 16.f, b.y * 16.f);
    unsigned p3 = cvt2fp8(b.z * 16.f, b.w * 16.f);
    int row = i >> 6, g = i & 63;
    int pos = (g >> 3) * 64 + (g & 3) * 16 + (g & 4) * 2;  // permpos of granule start
    u8* dst = Xq + (size_t)row * 512 + pos;
    *(unsigned*)dst = p0 | (p1 << 16);
    *(unsigned*)(dst + 4) = p2 | (p3 << 16);
  } else if (bid < 4928) {
    int id = bid - 3840;
    int mid = id >> 6, tile = id & 63;
    const float* src;
    if (mid == 0) src = fc1;
    else if (mid == 1) src = fc2;
    else if (mid < 8) src = ew1 + (size_t)(mid - 2) * 262144;
    else if (mid < 14) src = ew2 + (size_t)(mid - 8) * 262144;
    else src = tw1 + (size_t)(mid - 14) * 262144;
    int tr = (tile >> 3) * 64, tc = (tile & 7) * 64;
    __shared__ float t[64][65];
    int c = threadIdx.x & 63, r0 = threadIdx.x >> 6;
#pragma unroll
    for (int i = 0; i < 16; i++) {
      int r = r0 + i * 4;
      t[r][c] = src[(size_t)(tr + r) * 512 + tc + c];
    }
    __syncthreads();
    u8* dq;
    if (mid == 0) dq = fc1q;
    else if (mid == 1) dq = fc2q;
    else if (mid < 8) dq = w1q + (size_t)(mid - 2) * 262144;
    else if (mid < 14) dq = w2q + (size_t)(mid - 8) * 262144;
    else dq = tw1q + (size_t)(mid - 14) * 262144;
    int pc = tr + permpos(c);   // tr is a multiple of 64
#pragma unroll
    for (int i = 0; i < 16; i++) {
      int r = r0 + i * 4;
      dq[(size_t)(tc + r) * 512 + pc] = (u8)(cvt2fp8(t[c][r] * 64.f, 0.f) & 0xff);
    }
  } else if (bid < 4960) {
    int col = bid - 4928;  // 0..31
    for (int k = threadIdx.x; k < 512; k += 256) {
      float v = 0.f;
      if (col < 18) {
        int t = col / 6, e = col % 6;
        v = wg[(size_t)(t * 512 + k) * 6 + e];
      }
      int pos = (k & ~63) + permpos(k & 63);
      wgq[(size_t)col * 512 + pos] = (u8)(cvt2fp8(v * 64.f, 0.f) & 0xff);
    }
  } else {
    int i = (bid - 4960) * 1024 + threadIdx.x * 4;
    float4 z; z.x = 0.f; z.y = 0.f; z.z = 0.f; z.w = 0.f;
    *(float4*)(logits + i) = z;
  }
}

// ===== generic fp8 GEMM, BM=64 BN=128 BK=64, 8 K-steps (tower-proven template) =====
// Cq = fp8((relu?)(P/1024 + bias) * 16)
template <int RELU>
__global__ __launch_bounds__(256, 2) void gemm_s8(
    const u8* __restrict__ Aq,
    const u8* __restrict__ Bq,
    const float* __restrict__ bias,
    u8* __restrict__ Cq) {
  int nwg = gridDim.x, cpx = nwg >> 3;
  int bid = blockIdx.x;
  int swz = (bid & 7) * cpx + (bid >> 3);
  int bx = swz >> 2, by = swz & 3;
  int brow = bx * 64, bcol = by * 128;

  __shared__ __align__(16) u8 SB8[3][12288];

  int tid = threadIdx.x, lane = tid & 63, w = tid >> 6;
  int l = lane & 15, q = lane >> 4;

  int srow = tid >> 2, sc = tid & 3;
  int scX = sc ^ ((srow >> 1) & 3);
  const u8* Ag = Aq + (size_t)(brow + srow) * 512 + scX * 16;
  const u8* Bg0 = Bq + (size_t)(bcol + srow) * 512 + scX * 16;
  const u8* Bg1 = Bg0 + (size_t)64 * 512;
  int lo = w * 1024;

#define STAGES(buf, kt)                                \
  do {                                                 \
    gload16(Ag + (kt) * 64, (buf) + lo);               \
    gload16(Bg0 + (kt) * 64, (buf) + 4096 + lo);       \
    gload16(Bg1 + (kt) * 64, (buf) + 8192 + lo);       \
  } while (0)

  f32x4 P[4][2];
#pragma unroll
  for (int mi = 0; mi < 4; mi++)
#pragma unroll
    for (int ni = 0; ni < 2; ni++) {
      P[mi][ni][0] = 0.f; P[mi][ni][1] = 0.f; P[mi][ni][2] = 0.f; P[mi][ni][3] = 0.f;
    }

  int xg = q ^ ((l >> 1) & 3);

  STAGES(SB8[0], 0);
  STAGES(SB8[1], 1);
  asm volatile("s_waitcnt vmcnt(3)" ::: "memory");
  __builtin_amdgcn_s_barrier();

  u8 *bc = SB8[0], *bn = SB8[1], *bq = SB8[2];
#pragma unroll
  for (int kt = 0; kt < 8; ++kt) {
    if (kt < 6) STAGES(bq, kt + 2);
    i64x2 bfv[2], afv[4];
#pragma unroll
    for (int ni = 0; ni < 2; ni++) {
      int col = w * 32 + ni * 16 + l;
      bfv[ni] = *(const i64x2*)&bc[4096 + col * 64 + xg * 16];
    }
#pragma unroll
    for (int mi = 0; mi < 4; mi++) {
      int row = mi * 16 + l;
      afv[mi] = *(const i64x2*)&bc[row * 64 + xg * 16];
    }
    __builtin_amdgcn_s_setprio(1);
#pragma unroll
    for (int ks = 0; ks < 2; ++ks)
#pragma unroll
      for (int mi = 0; mi < 4; mi++)
#pragma unroll
        for (int ni = 0; ni < 2; ni++)
          P[mi][ni] = __builtin_amdgcn_mfma_f32_16x16x32_fp8_fp8(
              afv[mi][ks], bfv[ni][ks], P[mi][ni], 0, 0, 0);
    __builtin_amdgcn_s_setprio(0);
    asm volatile("s_waitcnt lgkmcnt(0)" ::: "memory");
    if (kt < 6)
      asm volatile("s_waitcnt vmcnt(3)" ::: "memory");
    else
      asm volatile("s_waitcnt vmcnt(0)" ::: "memory");
    __builtin_amdgcn_s_barrier();
    u8* t_ = bc; bc = bn; bn = bq; bq = t_;
  }
#undef STAGES

  float bvs[2];
#pragma unroll
  for (int ni = 0; ni < 2; ni++) bvs[ni] = bias[bcol + w * 32 + ni * 16 + l];

  u8* S8 = (u8*)&SB8[0][0];   // 64*144 = 9216 B
#pragma unroll
  for (int mi = 0; mi < 4; mi++) {
    int rl = mi * 16 + q * 4;
#pragma unroll
    for (int ni = 0; ni < 2; ni++) {
      int colL = w * 32 + ni * 16 + l;
      int pc = (colL & 64) + permpos(colL & 63);
      float v[4];
#pragma unroll
      for (int rr = 0; rr < 4; rr++) {
        float x = P[mi][ni][rr] * 9.765625e-4f + bvs[ni];
        if (RELU) x = fmaxf(x, 0.f);
        v[rr] = x;
      }
      unsigned p01 = cvt2fp8(v[0] * 16.f, v[1] * 16.f);
      unsigned p23 = cvt2fp8(v[2] * 16.f, v[3] * 16.f);
      S8[(rl + 0) * 144 + pc] = (u8)(p01 & 0xff);
      S8[(rl + 1) * 144 + pc] = (u8)(p01 >> 8);
      S8[(rl + 2) * 144 + pc] = (u8)(p23 & 0xff);
      S8[(rl + 3) * 144 + pc] = (u8)(p23 >> 8);
    }
  }
  __syncthreads();
  {
    int row_ = tid >> 2, cc_ = tid & 3;
#pragma unroll
    for (int j = 0; j < 2; j++)
      *(u8x16*)&Cq[(size_t)(brow + row_) * 512 + bcol + j * 64 + cc_ * 16] =
          *(const u8x16*)&S8[row_ * 144 + j * 64 + cc_ * 16];
  }
}

// ===== gate fp8: glog = hq @ wgq / 1024, top3 softmax -> gates =====
__global__ __launch_bounds__(256) void gate_kernel(const u8* __restrict__ hq,
                                                   const u8* __restrict__ wgq,
                                                   float* __restrict__ gates) {
  __shared__ __align__(16) u8 SBg[2][6144];  // per buf: A 0..4095, B 4096..6143
  __shared__ float Gl[4][16][33];
  int tid = threadIdx.x, lane = tid & 63, w = tid >> 6;
  int l = lane & 15, q = lane >> 4;
  int brow = blockIdx.x * 64;

  int srow = tid >> 2, sc = tid & 3;
  int scA = sc ^ ((srow >> 1) & 3);
  const u8* Ag = hq + (size_t)(brow + srow) * 512 + scA * 16;
  int Brow = srow & 31;
  int scB = sc ^ ((Brow >> 1) & 3);
  const u8* Bg = wgq + (size_t)Brow * 512 + scB * 16;
  int loA = w * 1024;
  int loB = 4096 + w * 1024;   // only waves 0,1

#define STAGEG(buf, kt)                                \
  do {                                                 \
    gload16(Ag + (kt) * 64, (buf) + loA);              \
    if (w < 2) gload16(Bg + (kt) * 64, (buf) + loB);   \
  } while (0)

  f32x4 acc0, acc1;
  acc0[0] = acc0[1] = acc0[2] = acc0[3] = 0.f;
  acc1 = acc0;
  int xg = q ^ ((l >> 1) & 3);
  int arow = w * 16 + l;

  STAGEG(SBg[0], 0);
  asm volatile("s_waitcnt vmcnt(0)" ::: "memory");
  __builtin_amdgcn_s_barrier();

#pragma unroll
  for (int s = 0; s < 8; ++s) {
    u8* bc = SBg[s & 1];
    if (s < 7) STAGEG(SBg[(s + 1) & 1], s + 1);
    i64x2 a = *(const i64x2*)&bc[arow * 64 + xg * 16];
    i64x2 b0 = *(const i64x2*)&bc[4096 + l * 64 + xg * 16];
    i64x2 b1 = *(const i64x2*)&bc[4096 + (16 + l) * 64 + xg * 16];
#pragma unroll
    for (int ks = 0; ks < 2; ++ks) {
      acc0 = __builtin_amdgcn_mfma_f32_16x16x32_fp8_fp8(a[ks], b0[ks], acc0, 0, 0, 0);
      acc1 = __builtin_amdgcn_mfma_f32_16x16x32_fp8_fp8(a[ks], b1[ks], acc1, 0, 0, 0);
    }
    asm volatile("s_waitcnt lgkmcnt(0)" ::: "memory");
    asm volatile("s_waitcnt vmcnt(0)" ::: "memory");
    __builtin_amdgcn_s_barrier();
  }
#undef STAGEG

#pragma unroll
  for (int rr = 0; rr < 4; rr++) {
    Gl[w][q * 4 + rr][l] = acc0[rr] * 9.765625e-4f;
    Gl[w][q * 4 + rr][16 + l] = acc1[rr] * 9.765625e-4f;
  }
  __syncthreads();

  if (lane < 16) {
    int R = brow + w * 16 + lane;
    int b = R / CDIM, c = R % CDIM;
    for (int t = 0; t < 3; t++) {
      float g[6];
#pragma unroll
      for (int e = 0; e < 6; e++) g[e] = Gl[w][lane][t * 6 + e];
      float out[6] = {0, 0, 0, 0, 0, 0};
      int idx[3]; float val[3];
      unsigned used = 0;
      for (int kk = 0; kk < 3; kk++) {
        int best = 0; float bv = -1e30f;
        for (int e = 0; e < 6; e++)
          if (!((used >> e) & 1) && g[e] > bv) { bv = g[e]; best = e; }
        used |= 1u << best; idx[kk] = best; val[kk] = bv;
      }
      float mx = val[0];
      float s = 0.f, ex[3];
      for (int kk = 0; kk < 3; kk++) { ex[kk] = expf(val[kk] - mx); s += ex[kk]; }
      for (int kk = 0; kk < 3; kk++) out[idx[kk]] = ex[kk] / s;
      float* gp = &gates[(size_t)((b * TDIM + t) * CDIM + c) * EDIM];
      for (int e = 0; e < 6; e++) gp[e] = out[e];
    }
  }
}

// ===== W1 fp8: 128x256 tile, BK=64, 8 K-steps, triple-buffer counted vmcnt =====
__global__ __launch_bounds__(512, 4) void gemm256q(
    const u8* __restrict__ Aq,
    const u8* __restrict__ Bq,
    const float* __restrict__ bias,
    u8* __restrict__ Cq,
    int nby) {
  int nwg = gridDim.x;
  int cpx = nwg >> 3;
  int bid = blockIdx.x;
  int swz = (bid & 7) * cpx + (bid >> 3);
  int bx = swz / nby, by = swz % nby;
  int brow = bx * 128, bcol = by * 256;

  __shared__ __align__(16) u8 SB8[3][24576];  // A 0..8191, B 8192..24575

  int tid = threadIdx.x, lane = tid & 63, w = tid >> 6;
  int wm = w >> 2, wn = w & 3;
  int l = lane & 15, q = lane >> 4;

  int srow = tid >> 2, sc = tid & 3;
  int scX = sc ^ ((srow >> 1) & 3);
  const u8* Ag = Aq + (size_t)(brow + srow) * 512 + scX * 16;
  const u8* Bg0 = Bq + (size_t)(bcol + srow) * 512 + scX * 16;
  const u8* Bg1 = Bg0 + (size_t)128 * 512;
  int lo = w * 1024;

#define STAGEQ(buf, kt)                                \
  do {                                                 \
    gload16(Ag + (kt) * 64, (buf) + lo);               \
    gload16(Bg0 + (kt) * 64, (buf) + 8192 + lo);       \
    gload16(Bg1 + (kt) * 64, (buf) + 16384 + lo);      \
  } while (0)

  f32x4 acc[4][4];
#pragma unroll
  for (int m = 0; m < 4; m++)
#pragma unroll
    for (int n = 0; n < 4; n++) {
      acc[m][n][0] = 0.f; acc[m][n][1] = 0.f; acc[m][n][2] = 0.f; acc[m][n][3] = 0.f;
    }

  int xg = q ^ ((l >> 1) & 3);

  STAGEQ(SB8[0], 0);
  STAGEQ(SB8[1], 1);
  asm volatile("s_waitcnt vmcnt(3)" ::: "memory");
  __builtin_amdgcn_s_barrier();

  u8 *bc = SB8[0], *bn = SB8[1], *bq = SB8[2];
#pragma unroll
  for (int kt = 0; kt < 8; ++kt) {
    if (kt < 6) STAGEQ(bq, kt + 2);
    i64x2 afv[4], bfv[4];
#pragma unroll
    for (int mi = 0; mi < 4; mi++) {
      int row = wm * 64 + mi * 16 + l;
      afv[mi] = *(const i64x2*)&bc[row * 64 + xg * 16];
    }
#pragma unroll
    for (int ni = 0; ni < 4; ni++) {
      int col = wn * 64 + ni * 16 + l;
      bfv[ni] = *(const i64x2*)&bc[8192 + col * 64 + xg * 16];
    }
    __builtin_amdgcn_s_setprio(1);
#pragma unroll
    for (int ks = 0; ks < 2; ++ks)
#pragma unroll
      for (int mi = 0; mi < 4; mi++)
#pragma unroll
        for (int ni = 0; ni < 4; ni++)
          acc[mi][ni] = __builtin_amdgcn_mfma_f32_16x16x32_fp8_fp8(
              afv[mi][ks], bfv[ni][ks], acc[mi][ni], 0, 0, 0);
    __builtin_amdgcn_s_setprio(0);
    asm volatile("s_waitcnt lgkmcnt(0)" ::: "memory");
    if (kt < 6)
      asm volatile("s_waitcnt vmcnt(3)" ::: "memory");
    else
      asm volatile("s_waitcnt vmcnt(0)" ::: "memory");
    __builtin_amdgcn_s_barrier();
    u8* t_ = bc; bc = bn; bn = bq; bq = t_;
  }
#undef STAGEQ

  u8* S8 = (u8*)&SB8[0][0];
  float bvs[4];
#pragma unroll
  for (int n = 0; n < 4; n++) bvs[n] = bias[bcol + wn * 64 + n * 16 + l];
#pragma unroll
  for (int m = 0; m < 4; m++) {
    int rl = wm * 64 + m * 16 + q * 4;
#pragma unroll
    for (int n = 0; n < 4; n++) {
      int pc = wn * 64 + permpos(n * 16 + l);
      float v0 = fmaxf(acc[m][n][0] * 9.765625e-4f + bvs[n], 0.f) * 16.f;
      float v1 = fmaxf(acc[m][n][1] * 9.765625e-4f + bvs[n], 0.f) * 16.f;
      float v2 = fmaxf(acc[m][n][2] * 9.765625e-4f + bvs[n], 0.f) * 16.f;
      float v3 = fmaxf(acc[m][n][3] * 9.765625e-4f + bvs[n], 0.f) * 16.f;
      unsigned p01 = cvt2fp8(v0, v1);
      unsigned p23 = cvt2fp8(v2, v3);
      S8[(rl + 0) * 264 + pc] = (u8)(p01 & 0xff);
      S8[(rl + 1) * 264 + pc] = (u8)(p01 >> 8);
      S8[(rl + 2) * 264 + pc] = (u8)(p23 & 0xff);
      S8[(rl + 3) * 264 + pc] = (u8)(p23 >> 8);
    }
  }
  __syncthreads();
  int row = tid >> 2, cc = tid & 3;
#pragma unroll
  for (int j = 0; j < 4; j++)
    *(u8x16*)&Cq[(size_t)(brow + row) * 3072 + bcol + cc * 64 + j * 16] =
        *(const u8x16*)&S8[row * 264 + cc * 64 + j * 16];
}

// ===== fused W2 + gated combine, fp8 (R14-proven: BM=64, BN=128, 960 blocks) =====
// launch_bounds MUST stay (256,2): (256,4) caps VGPR at 64 -> accumulator spill (R8).
__global__ __launch_bounds__(256, 2) void gemm_w2c(
    const u8* __restrict__ eh,       // [15360][3072] fp8 (x16), permuted
    const u8* __restrict__ W2q,      // [6][512 col][512 k] fp8 (x64), permuted
    const float* __restrict__ eb2,   // [6][512]
    const float* __restrict__ gates, // [(b*3+t)*30+c][6]
    u8* __restrict__ yq) {           // [3][15360][512] fp8 (x32), permuted
  int nwg = gridDim.x, cpx = nwg >> 3;
  int bid = blockIdx.x;
  int swz = (bid & 7) * cpx + (bid >> 3);
  int bx = swz >> 2, by = swz & 3;
  int brow = bx * 64, bcol = by * 128;

  __shared__ __align__(16) u8 SB8[3][12288];
  __shared__ u16 glds[64 * 18];

  int tid = threadIdx.x, lane = tid & 63, w = tid >> 6;
  int l = lane & 15, q = lane >> 4;

  for (int i = tid; i < 64 * 18; i += 256) {
    int r = i / 18, te = i % 18;
    int gr = brow + r, b = gr / CDIM, c = gr % CDIM;
    int t = te / 6, e = te % 6;
    glds[i] = f2bf(gates[((size_t)(b * TDIM + t) * CDIM + c) * EDIM + e]);
  }
  float b2all[2][6];
#pragma unroll
  for (int ni = 0; ni < 2; ni++) {
    int col = bcol + w * 32 + ni * 16 + l;
#pragma unroll
    for (int e = 0; e < 6; e++) b2all[ni][e] = eb2[e * 512 + col];
  }

  int srow = tid >> 2, sc = tid & 3;
  int scX = sc ^ ((srow >> 1) & 3);
  const u8* Ag = eh + (size_t)(brow + srow) * 3072 + scX * 16;
  const u8* Bg0 = W2q + (size_t)(bcol + srow) * 512 + scX * 16;
  const u8* Bg1 = Bg0 + (size_t)64 * 512;
  int lo = w * 1024;

#define STAGEW(buf, s2)                                                   \
  do {                                                                    \
    int _e2 = (s2) >> 3, _k2 = (s2) & 7;                                  \
    gload16(Ag + _e2 * 512 + _k2 * 64, (buf) + lo);                       \
    gload16(Bg0 + (size_t)_e2 * 262144 + _k2 * 64, (buf) + 4096 + lo);    \
    gload16(Bg1 + (size_t)_e2 * 262144 + _k2 * 64, (buf) + 8192 + lo);    \
  } while (0)

  f32x4 P[4][2], aY0[4][2], aY1[4][2], aY2[4][2];
#pragma unroll
  for (int mi = 0; mi < 4; mi++)
#pragma unroll
    for (int ni = 0; ni < 2; ni++) {
      P[mi][ni][0] = P[mi][ni][1] = P[mi][ni][2] = P[mi][ni][3] = 0.f;
      aY0[mi][ni] = P[mi][ni]; aY1[mi][ni] = P[mi][ni]; aY2[mi][ni] = P[mi][ni];
    }

  int xg = q ^ ((l >> 1) & 3);

  STAGEW(SB8[0], 0);
  STAGEW(SB8[1], 1);
  asm volatile("s_waitcnt vmcnt(3)" ::: "memory");
  __builtin_amdgcn_s_barrier();

  u8 *bc = SB8[0], *bn = SB8[1], *bq = SB8[2];
  for (int e = 0; e < 6; ++e) {
#pragma unroll
    for (int kt = 0; kt < 8; ++kt) {
      int s = e * 8 + kt;
      if (s < 46) STAGEW(bq, s + 2);
      i64x2 bfv[2], afv[4];
#pragma unroll
      for (int ni = 0; ni < 2; ni++) {
        int col = w * 32 + ni * 16 + l;
        bfv[ni] = *(const i64x2*)&bc[4096 + col * 64 + xg * 16];
      }
#pragma unroll
      for (int mi = 0; mi < 4; mi++) {
        int row = mi * 16 + l;
        afv[mi] = *(const i64x2*)&bc[row * 64 + xg * 16];
      }
      __builtin_amdgcn_s_setprio(1);
#pragma unroll
      for (int ks = 0; ks < 2; ++ks)
#pragma unroll
        for (int mi = 0; mi < 4; mi++)
#pragma unroll
          for (int ni = 0; ni < 2; ni++)
            P[mi][ni] = __builtin_amdgcn_mfma_f32_16x16x32_fp8_fp8(
                afv[mi][ks], bfv[ni][ks], P[mi][ni], 0, 0, 0);
      __builtin_amdgcn_s_setprio(0);
      asm volatile("s_waitcnt lgkmcnt(0)" ::: "memory");
      if (s < 46)
        asm volatile("s_waitcnt vmcnt(3)" ::: "memory");
      else
        asm volatile("s_waitcnt vmcnt(0)" ::: "memory");
      __builtin_amdgcn_s_barrier();
      u8* t_ = bc; bc = bn; bn = bq; bq = t_;
    }
#pragma unroll
    for (int mi = 0; mi < 4; mi++) {
#pragma unroll
      for (int rr = 0; rr < 4; rr++) {
        int row = mi * 16 + q * 4 + rr;
        float g0 = bf2f(glds[row * 18 + e]);
        float g1 = bf2f(glds[row * 18 + 6 + e]);
        float g2 = bf2f(glds[row * 18 + 12 + e]);
#pragma unroll
        for (int ni = 0; ni < 2; ni++) {
          float p = P[mi][ni][rr] * 9.765625e-4f + b2all[ni][e];
          aY0[mi][ni][rr] += g0 * p;
          aY1[mi][ni][rr] += g1 * p;
          aY2[mi][ni][rr] += g2 * p;
          P[mi][ni][rr] = 0.f;
        }
      }
    }
  }
#undef STAGEW

  u8* S8 = (u8*)&SB8[0][0];
#define EPI(AY, t)                                                          \
  do {                                                                      \
    _Pragma("unroll") for (int mi = 0; mi < 4; mi++) {                      \
      int rl = mi * 16 + q * 4;                                             \
      _Pragma("unroll") for (int ni = 0; ni < 2; ni++) {                    \
        int colL = w * 32 + ni * 16 + l;                                    \
        int pc = (colL & 64) + permpos(colL & 63);                          \
        unsigned p01 = cvt2fp8(AY[mi][ni][0] * 32.f, AY[mi][ni][1] * 32.f); \
        unsigned p23 = cvt2fp8(AY[mi][ni][2] * 32.f, AY[mi][ni][3] * 32.f); \
        S8[(rl + 0) * 144 + pc] = (u8)(p01 & 0xff);                         \
        S8[(rl + 1) * 144 + pc] = (u8)(p01 >> 8);                          \
        S8[(rl + 2) * 144 + pc] = (u8)(p23 & 0xff);                         \
        S8[(rl + 3) * 144 + pc] = (u8)(p23 >> 8);                          \
      }                                                                     \
    }                                                                       \
    __syncthreads();                                                        \
    {                                                                       \
      int row_ = tid >> 2, cc_ = tid & 3;                                   \
      _Pragma("unroll") for (int j = 0; j < 2; j++)                         \
        *(u8x16*)&yq[((size_t)(t) * NROWS + brow + row_) * 512 + bcol +     \
                     j * 64 + cc_ * 16] =                                   \
            *(const u8x16*)&S8[row_ * 144 + j * 64 + cc_ * 16];             \
    }                                                                       \
    __syncthreads();                                                        \
  } while (0)
  EPI(aY0, 0);
  EPI(aY1, 1);
  EPI(aY2, 2);
#undef EPI
}

// ===== tower fp8: th = relu(yq@tw1q/2048 + tb1); logits += th . tw2 =====
__global__ __launch_bounds__(256, 2) void gemm_tower(
    const u8* __restrict__ yq,
    const u8* __restrict__ tw1q,
    const float* __restrict__ tb1, const float* __restrict__ tw2,
    float* __restrict__ logits) {
  int t = blockIdx.z;
  const u8* A = yq + (size_t)t * NROWS * 512;
  const u8* BT = tw1q + (size_t)t * 262144;

  int nwg = gridDim.x, cpx = nwg >> 3;
  int bid = blockIdx.x;
  int swz = (bid & 7) * cpx + (bid >> 3);
  int bx = swz >> 2, by = swz & 3;
  int brow = bx * 64, bcol = by * 128;

  __shared__ __align__(16) u8 SB8[3][12288];

  int tid = threadIdx.x, lane = tid & 63, w = tid >> 6;
  int l = lane & 15, q = lane >> 4;

  int srow = tid >> 2, sc = tid & 3;
  int scX = sc ^ ((srow >> 1) & 3);
  const u8* Ag = A + (size_t)(brow + srow) * 512 + scX * 16;
  const u8* Bg0 = BT + (size_t)(bcol + srow) * 512 + scX * 16;
  const u8* Bg1 = Bg0 + (size_t)64 * 512;
  int lo = w * 1024;

#define STAGET(buf, kt)                                \
  do {                                                 \
    gload16(Ag + (kt) * 64, (buf) + lo);               \
    gload16(Bg0 + (kt) * 64, (buf) + 4096 + lo);       \
    gload16(Bg1 + (kt) * 64, (buf) + 8192 + lo);       \
  } while (0)

  f32x4 P[4][2];
#pragma unroll
  for (int mi = 0; mi < 4; mi++)
#pragma unroll
    for (int ni = 0; ni < 2; ni++) {
      P[mi][ni][0] = 0.f; P[mi][ni][1] = 0.f; P[mi][ni][2] = 0.f; P[mi][ni][3] = 0.f;
    }

  int xg = q ^ ((l >> 1) & 3);

  STAGET(SB8[0], 0);
  STAGET(SB8[1], 1);
  asm volatile("s_waitcnt vmcnt(3)" ::: "memory");
  __builtin_amdgcn_s_barrier();

  u8 *bc = SB8[0], *bn = SB8[1], *bq = SB8[2];
#pragma unroll
  for (int kt = 0; kt < 8; ++kt) {
    if (kt < 6) STAGET(bq, kt + 2);
    i64x2 bfv[2], afv[4];
#pragma unroll
    for (int ni = 0; ni < 2; ni++) {
      int col = w * 32 + ni * 16 + l;
      bfv[ni] = *(const i64x2*)&bc[4096 + col * 64 + xg * 16];
    }
#pragma unroll
    for (int mi = 0; mi < 4; mi++) {
      int row = mi * 16 + l;
      afv[mi] = *(const i64x2*)&bc[row * 64 + xg * 16];
    }
    __builtin_amdgcn_s_setprio(1);
#pragma unroll
    for (int ks = 0; ks < 2; ++ks)
#pragma unroll
      for (int mi = 0; mi < 4; mi++)
#pragma unroll
        for (int ni = 0; ni < 2; ni++)
          P[mi][ni] = __builtin_amdgcn_mfma_f32_16x16x32_fp8_fp8(
              afv[mi][ks], bfv[ni][ks], P[mi][ni], 0, 0, 0);
    __builtin_amdgcn_s_setprio(0);
    asm volatile("s_waitcnt lgkmcnt(0)" ::: "memory");
    if (kt < 6)
      asm volatile("s_waitcnt vmcnt(3)" ::: "memory");
    else
      asm volatile("s_waitcnt vmcnt(0)" ::: "memory");
    __builtin_amdgcn_s_barrier();
    u8* t_ = bc; bc = bn; bn = bq; bq = t_;
  }
#undef STAGET

  float bvs[2], tws[2];
#pragma unroll
  for (int ni = 0; ni < 2; ni++) {
    int col = bcol + w * 32 + ni * 16 + l;
    bvs[ni] = tb1[t * 512 + col];
    tws[ni] = tw2[t * 512 + col];
  }
#pragma unroll
  for (int mi = 0; mi < 4; mi++) {
#pragma unroll
    for (int rr = 0; rr < 4; rr++) {
      float s = 0.f;
#pragma unroll
      for (int ni = 0; ni < 2; ni++) {
        float v = P[mi][ni][rr] * 4.8828125e-4f + bvs[ni];
        v = fmaxf(v, 0.f);
        s += v * tws[ni];
      }
      s += __shfl_xor(s, 1, 64);
      s += __shfl_xor(s, 2, 64);
      s += __shfl_xor(s, 4, 64);
      s += __shfl_xor(s, 8, 64);
      if (l == 0) {
        int row = brow + mi * 16 + q * 4 + rr;
        int b = row / CDIM, c = row % CDIM;
        atomicAdd(&logits[(size_t)(b * TDIM + t) * CDIM + c], s);
      }
    }
  }
}

// ---------------- loss: one wave per b ----------------
__global__ __launch_bounds__(64) void loss_kernel(const float* __restrict__ scores,
                                                  const float* __restrict__ logits,
                                                  const float* __restrict__ gates,
                                                  const float* __restrict__ tb2,
                                                  float* __restrict__ out) {
  int b = blockIdx.x;
  int lane = threadIdx.x;
  float bce_sum = 0.f;
  float aux = 0.f;
  for (int t = 0; t < 3; t++) {
    float sc = (lane < CDIM) ? scores[(size_t)(b * TDIM + t) * CDIM + lane] : -1e30f;
    float mx = sc;
    for (int off = 32; off; off >>= 1) mx = fmaxf(mx, __shfl_xor(mx, off, 64));
    float lab = (lane < CDIM && sc == mx) ? 1.f : 0.f;
    float lg = (lane < CDIM) ? (logits[(size_t)(b * TDIM + t) * CDIM + lane] + tb2[t]) : 0.f;
    float bce = (lane < CDIM) ? (fmaxf(lg, 0.f) - lg * lab + log1pf(expf(-fabsf(lg)))) : 0.f;
    for (int off = 32; off; off >>= 1) bce += __shfl_xor(bce, off, 64);
    bce_sum += bce / (float)CDIM;

    float impv[6];
    float meansum = 0.f;
#pragma unroll
    for (int e = 0; e < 6; e++) {
      float gsum = (lane < CDIM) ? gates[(size_t)((b * TDIM + t) * CDIM + lane) * EDIM + e] : 0.f;
      for (int off = 32; off; off >>= 1) gsum += __shfl_xor(gsum, off, 64);
      impv[e] = gsum;
      meansum += gsum;
    }
    float mean = meansum / 6.f;
    float var = 0.f;
#pragma unroll
    for (int e = 0; e < 6; e++) { float d = impv[e] - mean; var += d * d; }
    var /= 6.f;
    aux += var / (mean * mean + 1e-10f);
  }
  float res = bce_sum / 3.f + 0.01f * aux;
  if (lane == 0) atomicAdd(out, res / (float)BDIM);
}

// ---------------- host ----------------
extern "C" void kernel_launch(void* const* d_in, const int* in_sizes, int n_in,
                              void* d_out, int out_size, void* d_ws, size_t ws_size,
                              hipStream_t stream) {
  const float* X = (const float*)d_in[0];
  const float* scores = (const float*)d_in[1];
  const float* fc1_w = (const float*)d_in[2];
  const float* fc1_b = (const float*)d_in[3];
  const float* fc2_w = (const float*)d_in[4];
  const float* fc2_b = (const float*)d_in[5];
  const float* w_gate = (const float*)d_in[6];
  const float* ew1 = (const float*)d_in[7];
  const float* eb1 = (const float*)d_in[8];
  const float* ew2 = (const float*)d_in[9];
  const float* eb2 = (const float*)d_in[10];
  const float* tw1 = (const float*)d_in[11];
  const float* tb1 = (const float*)d_in[12];
  const float* tw2 = (const float*)d_in[13];
  const float* tb2 = (const float*)d_in[14];
  float* out = (float*)d_out;

  // workspace layout (all disjoint)
  u8* fc1q = (u8*)d_ws;                          // 262144
  u8* fc2q = fc1q + 262144;                      // 262144
  u8* w1q = fc2q + 262144;                       // 6*262144
  u8* w2q = w1q + (size_t)6 * 262144;            // 6*262144
  u8* tw1q = w2q + (size_t)6 * 262144;           // 3*262144
  u8* wgq = tw1q + (size_t)3 * 262144;           // 32*512
  u8* Xq = wgq + (size_t)32 * 512;               // [15360][512]
  u8* A1q = Xq + (size_t)NROWS * 512;            // [15360][512]
  u8* hq = A1q + (size_t)NROWS * 512;            // [15360][512]
  u8* ehq = hq + (size_t)NROWS * 512;            // [15360][3072]
  u8* yq = ehq + (size_t)NROWS * 3072;           // [3][15360][512]
  float* gates = (float*)(yq + (size_t)TDIM * NROWS * 512);
  float* logits = gates + (size_t)BDIM * TDIM * CDIM * EDIM;

  hipMemsetAsync(d_out, 0, sizeof(float) * out_size, stream);

  // merged prep: X -> fp8, all weights + gate weights -> fp8, zero logits
  prep_kernel<<<5005, 256, 0, stream>>>(X, Xq, fc1_w, fc2_w, ew1, ew2, tw1,
                                        fc1q, fc2q, w1q, w2q, tw1q, w_gate, wgq, logits);

  // shared bottom fp8 (960 blocks of 64x128, 8 K-steps)
  gemm_s8<1><<<dim3(960), 256, 0, stream>>>(Xq, fc1q, fc1_b, A1q);   // relu
  gemm_s8<0><<<dim3(960), 256, 0, stream>>>(A1q, fc2q, fc2_b, hq);   // no relu

  // gating fp8 (240 blocks)
  gate_kernel<<<240, 256, 0, stream>>>(hq, wgq, gates);

  // experts W1 fp8: merged N=3072 (1440 blocks of 128x256, 8 K-steps) -> ehq
  gemm256q<<<dim3(1440), 512, 0, stream>>>(hq, w1q, eb1, ehq, 12);

  // experts W2 + gated combine, fp8 (960 blocks of 64x128, 48 K-steps) -> yq
  gemm_w2c<<<dim3(960), 256, 0, stream>>>(ehq, w2q, eb2, gates, yq);

  // towers fp8 (960 x 3 blocks of 64x128, 8 K-steps) -> logits (atomic)
  gemm_tower<<<dim3(960, 1, 3), 256, 0, stream>>>(yq, tw1q, tb1, tw2, logits);

  // loss
  loss_kernel<<<BDIM, 64, 0, stream>>>(scores, logits, gates, tb2, out);
}